// Round 2
// baseline (338.818 us; speedup 1.0000x reference)
//
#include <hip/hip_runtime.h>
#include <hip/hip_bf16.h>
#include <stdint.h>
#include <type_traits>

// ---------------------------------------------------------------------------
// Fused attention: out = softmax((x Wq^T)(x Wk^T)^T / sqrt(d)) (x Wv^T)
// B=4, S=2048, D=1024, fp32 in/out, bf16 MFMA internal compute.
//
// R2: GEMM engine upgraded to 256-class tile, BK=64, 8 waves, 4-phase
// barrier-locked schedule with per-phase global_load_lds prefetch into a
// double buffer, setprio around MFMA clusters, vmcnt(0) drain once per
// K-tile boundary. All GEMM grids are exactly 256 blocks (1 per CU).
// ---------------------------------------------------------------------------

typedef __attribute__((ext_vector_type(8))) short short8;
typedef __attribute__((ext_vector_type(4))) float f32x4;

#define GL_G(p) ((const __attribute__((address_space(1))) void*)(p))
#define GL_L(p) ((__attribute__((address_space(3))) void*)(p))

__device__ __forceinline__ float bf2f(unsigned short u) {
  union { float f; uint32_t i; } c; c.i = ((uint32_t)u) << 16; return c.f;
}
__device__ __forceinline__ unsigned short f2bf(float f) {
  __hip_bfloat16 h = __float2bfloat16(f);
  return *reinterpret_cast<unsigned short*>(&h);
}

// ---------------- cast fp32 -> bf16 (vectorized) ----------------
__global__ __launch_bounds__(256) void cast_f32_to_bf16(
    const float* __restrict__ in, unsigned short* __restrict__ out, long n) {
  long tid = (long)blockIdx.x * blockDim.x + threadIdx.x;
  long stride = (long)gridDim.x * blockDim.x;
  for (long j = tid * 8; j < n; j += stride * 8) {
    float4 a = *(const float4*)(in + j);
    float4 b = *(const float4*)(in + j + 4);
    uint4 pk;
    pk.x = (uint32_t)f2bf(a.x) | ((uint32_t)f2bf(a.y) << 16);
    pk.y = (uint32_t)f2bf(a.z) | ((uint32_t)f2bf(a.w) << 16);
    pk.z = (uint32_t)f2bf(b.x) | ((uint32_t)f2bf(b.y) << 16);
    pk.w = (uint32_t)f2bf(b.z) | ((uint32_t)f2bf(b.w) << 16);
    *(uint4*)(out + j) = pk;
  }
}

// ---------------- NT GEMM, 256xBN tile, BK=64, 512 threads ----------------
// C[m,n] = scale * sum_k A[m,k] B[n,k].  A:[M x K] bf16 (ldA), B:[N x K] (ldB)
// Requires M%256==0, N%BN==0, K%64==0. Grid: 1D, nbm*nbn*nz blocks.
template <int BN, typename OUT_T, bool TRANS>
__global__ __launch_bounds__(512) void gemm8(
    const unsigned short* __restrict__ A, const unsigned short* __restrict__ B,
    OUT_T* __restrict__ C, int K, int ldA, int ldB, int ldC,
    long sA, long sB, long sC, float scale, int nbm, int nbn) {
  constexpr int BM = 256, BK = 64;
  constexpr int WVN = BN / 4;              // per-wave N (64 or 32)
  constexpr int NREP = WVN / 16;           // 4 or 2
  constexpr int NH = NREP / 2;             // 2 or 1 (n-frags per phase)
  constexpr int ACH = BM * BK * 2 / 8192;  // 4 A-chunks (64 rows each)
  constexpr int BCH = BN * BK * 2 / 8192;  // 4 or 2 B-chunks
  constexpr int TC = ACH + BCH;

  __shared__ unsigned short As[2][BM * BK];
  __shared__ unsigned short Bs[2][BN * BK];

  const int tid = threadIdx.x;
  const int wid = tid >> 6, lane = tid & 63;
  const int wm = wid >> 2, wn = wid & 3;
  const int fr = lane & 15, kg = (lane >> 4) * 8;

  // XCD-aware bijective swizzle (gridDim.x is always a multiple of 8 here),
  // n-major decode so consecutive logical tiles share the A panel.
  const int NB = gridDim.x;
  const int p = blockIdx.x;
  const int l = (p & 7) * (NB >> 3) + (p >> 3);
  const int pb = nbm * nbn;
  const int z = l / pb;
  const int mn = l - z * pb;
  const int bm = mn / nbn, bn = mn - bm * nbn;
  A += (long)z * sA; B += (long)z * sB; C += (long)z * sC;
  const long brow = (long)bm * BM, bcol = (long)bn * BN;

  // staging coords: chunk = 64 rows x 128B; thread tid supplies 16B at
  // linear offset tid*16 (dest = wave-uniform base, HW adds lane*16).
  const int srow = tid >> 3;
  const int scolb = (tid & 7) * 16;

  f32x4 acc[8][NREP];
#pragma unroll
  for (int m = 0; m < 8; ++m)
#pragma unroll
    for (int n = 0; n < NREP; ++n) acc[m][n] = (f32x4){0.f, 0.f, 0.f, 0.f};

  const char* aB = (const char*)A;
  const char* bB = (const char*)B;

  auto stageChunk = [&](int buf, int kt, int c) {
    if (c < ACH) {
      const char* g = aB + ((brow + c * 64 + srow) * (long)ldA + kt) * 2 + scolb;
      __builtin_amdgcn_global_load_lds(
          GL_G(g), GL_L((char*)&As[buf][0] + c * 8192 + wid * 1024), 16, 0, 0);
    } else {
      const int cc = c - ACH;
      const char* g = bB + ((bcol + cc * 64 + srow) * (long)ldB + kt) * 2 + scolb;
      __builtin_amdgcn_global_load_lds(
          GL_G(g), GL_L((char*)&Bs[buf][0] + cc * 8192 + wid * 1024), 16, 0, 0);
    }
  };

  const int nt = K / BK;
  // prologue: stage tile 0 into buffer 0
#pragma unroll
  for (int c = 0; c < TC; ++c) stageChunk(0, 0, c);
  asm volatile("s_waitcnt vmcnt(0)" ::: "memory");
  __builtin_amdgcn_s_barrier();
  asm volatile("" ::: "memory");

  for (int t = 0; t < nt; ++t) {
    const int cur = t & 1;
    const int ktn = (t + 1) * BK;
    const bool more = (t + 1 < nt);
#pragma unroll
    for (int ph = 0; ph < 4; ++ph) {
      const int mh = ph >> 1, nh = ph & 1;
      // ds-load this phase's register subtile (from buf[cur])
      short8 af[4][2], bfx[NH][2];
#pragma unroll
      for (int i = 0; i < 4; ++i)
#pragma unroll
        for (int ks = 0; ks < 2; ++ks)
          af[i][ks] = *(const short8*)&As[cur][(wm * 128 + (mh * 4 + i) * 16 + fr) * BK + ks * 32 + kg];
#pragma unroll
      for (int j = 0; j < NH; ++j)
#pragma unroll
        for (int ks = 0; ks < 2; ++ks)
          bfx[j][ks] = *(const short8*)&Bs[cur][(wn * WVN + (nh * NH + j) * 16 + fr) * BK + ks * 32 + kg];
      // prefetch a slice of the next K-tile into buf[cur^1]
      if (more) {
#pragma unroll
        for (int c = (ph * TC) >> 2; c < ((ph + 1) * TC) >> 2; ++c)
          stageChunk(cur ^ 1, ktn, c);
      }
      asm volatile("" ::: "memory");
      __builtin_amdgcn_s_barrier();
      asm volatile("" ::: "memory");
      __builtin_amdgcn_s_setprio(1);
#pragma unroll
      for (int i = 0; i < 4; ++i)
#pragma unroll
        for (int j = 0; j < NH; ++j)
#pragma unroll
          for (int ks = 0; ks < 2; ++ks)
            acc[mh * 4 + i][nh * NH + j] = __builtin_amdgcn_mfma_f32_16x16x32_bf16(
                af[i][ks], bfx[j][ks], acc[mh * 4 + i][nh * NH + j], 0, 0, 0);
      __builtin_amdgcn_s_setprio(0);
      asm volatile("" ::: "memory");
      __builtin_amdgcn_s_barrier();
      asm volatile("" ::: "memory");
    }
    // K-tile boundary: next buffer must be fully landed before its ds_reads
    if (more) {
      asm volatile("s_waitcnt vmcnt(0)" ::: "memory");
      __builtin_amdgcn_s_barrier();
      asm volatile("" ::: "memory");
    }
  }

  // epilogue: C/D layout col = lane&15, row = (lane>>4)*4 + r
#pragma unroll
  for (int m = 0; m < 8; ++m) {
    const long rowg0 = brow + wm * 128 + m * 16 + (lane >> 4) * 4;
#pragma unroll
    for (int n = 0; n < NREP; ++n) {
      const long colg = bcol + wn * WVN + n * 16 + fr;
      f32x4 v = acc[m][n];
      if constexpr (TRANS) {
        ushort4 pk;
        pk.x = f2bf(v[0] * scale);
        pk.y = f2bf(v[1] * scale);
        pk.z = f2bf(v[2] * scale);
        pk.w = f2bf(v[3] * scale);
        *(ushort4*)((unsigned short*)C + colg * ldC + rowg0) = pk;
      } else {
#pragma unroll
        for (int r = 0; r < 4; ++r) {
          float val = v[r] * scale;
          if constexpr (std::is_same<OUT_T, float>::value)
            C[(rowg0 + r) * ldC + colg] = val;
          else
            C[(rowg0 + r) * ldC + colg] = f2bf(val);
        }
      }
    }
  }
}

// ---------------- row softmax in-place on bf16 [rows x 2048] ----------------
__global__ __launch_bounds__(256) void softmax_inplace(
    unsigned short* __restrict__ S) {
  unsigned short* row = S + (size_t)blockIdx.x * 2048;
  const int tid = threadIdx.x;
  const int wid = tid >> 6;
  const int lane = tid & 63;

  uint4 raw = *(const uint4*)(row + tid * 8);
  float v[8];
  v[0] = bf2f(raw.x & 0xffff); v[1] = bf2f(raw.x >> 16);
  v[2] = bf2f(raw.y & 0xffff); v[3] = bf2f(raw.y >> 16);
  v[4] = bf2f(raw.z & 0xffff); v[5] = bf2f(raw.z >> 16);
  v[6] = bf2f(raw.w & 0xffff); v[7] = bf2f(raw.w >> 16);

  float mx = v[0];
#pragma unroll
  for (int i = 1; i < 8; ++i) mx = fmaxf(mx, v[i]);
#pragma unroll
  for (int off = 32; off; off >>= 1) mx = fmaxf(mx, __shfl_xor(mx, off));

  __shared__ float sred[8];
  if (lane == 0) sred[wid] = mx;
  __syncthreads();
  mx = fmaxf(fmaxf(sred[0], sred[1]), fmaxf(sred[2], sred[3]));

  float e[8];
  float s = 0.f;
#pragma unroll
  for (int i = 0; i < 8; ++i) {
    e[i] = __expf(v[i] - mx);
    s += e[i];
  }
#pragma unroll
  for (int off = 32; off; off >>= 1) s += __shfl_xor(s, off);
  if (lane == 0) sred[4 + wid] = s;
  __syncthreads();
  s = (sred[4] + sred[5]) + (sred[6] + sred[7]);
  float inv = 1.0f / s;

  uint4 pk;
  pk.x = (uint32_t)f2bf(e[0] * inv) | ((uint32_t)f2bf(e[1] * inv) << 16);
  pk.y = (uint32_t)f2bf(e[2] * inv) | ((uint32_t)f2bf(e[3] * inv) << 16);
  pk.z = (uint32_t)f2bf(e[4] * inv) | ((uint32_t)f2bf(e[5] * inv) << 16);
  pk.w = (uint32_t)f2bf(e[6] * inv) | ((uint32_t)f2bf(e[7] * inv) << 16);
  *(uint4*)(row + tid * 8) = pk;
}

// ---------------------------------------------------------------------------
extern "C" void kernel_launch(void* const* d_in, const int* in_sizes, int n_in,
                              void* d_out, int out_size, void* d_ws,
                              size_t ws_size, hipStream_t stream) {
  const float* x = (const float*)d_in[0];
  const float* Wq = (const float*)d_in[1];
  const float* Wk = (const float*)d_in[2];
  const float* Wv = (const float*)d_in[3];
  float* out = (float*)d_out;

  const long XE = 4L * 2048 * 1024;  // 8,388,608 elems
  const long WE = 1024L * 1024;      // 1,048,576 elems
  const long SE = 4L * 2048 * 2048;  // 16,777,216 elems

  unsigned short* xb = (unsigned short*)d_ws;
  unsigned short* Wqb = xb + XE;
  unsigned short* Wkb = Wqb + WE;
  unsigned short* Wvb = Wkb + WE;
  unsigned short* Qb = Wvb + WE;
  unsigned short* Kb = Qb + XE;
  unsigned short* Vtb = Kb + XE;   // [b][e][s] (transposed V)
  unsigned short* Sb = Vtb + XE;   // [b][q][k] scores -> probs
  if (ws_size < (size_t)(4 * XE + 3 * WE + SE) * 2) return;  // loud failure

  cast_f32_to_bf16<<<1024, 256, 0, stream>>>(x, xb, XE);
  cast_f32_to_bf16<<<256, 256, 0, stream>>>(Wq, Wqb, WE);
  cast_f32_to_bf16<<<256, 256, 0, stream>>>(Wk, Wkb, WE);
  cast_f32_to_bf16<<<256, 256, 0, stream>>>(Wv, Wvb, WE);

  // Q = xb Wq^T  [8192 x 1024] : 32x8 tiles of 256x128 = 256 blocks
  gemm8<128, unsigned short, false><<<256, 512, 0, stream>>>(
      xb, Wqb, Qb, 1024, 1024, 1024, 1024, 0, 0, 0, 1.0f, 32, 8);
  // K = xb Wk^T
  gemm8<128, unsigned short, false><<<256, 512, 0, stream>>>(
      xb, Wkb, Kb, 1024, 1024, 1024, 1024, 0, 0, 0, 1.0f, 32, 8);
  // Vt[b][e][s] = (xb Wv^T)^T, per batch: 8x8x4 = 256 blocks
  gemm8<128, unsigned short, true><<<256, 512, 0, stream>>>(
      xb, Wvb, Vtb, 1024, 1024, 1024, 2048, 2048L * 1024, 0, 1024L * 2048,
      1.0f, 8, 8);
  // S[b][q][k] = Qb Kb^T / 32, per batch: 8x8x4 = 256 blocks (256x256 tile)
  gemm8<256, unsigned short, false><<<256, 512, 0, stream>>>(
      Qb, Kb, Sb, 1024, 1024, 1024, 2048, 2048L * 1024, 2048L * 1024,
      2048L * 2048, 0.03125f, 8, 8);
  // softmax rows (4*2048 rows of 2048)
  softmax_inplace<<<8192, 256, 0, stream>>>(Sb);
  // out[b][q][e] = P Vt^T, per batch: 8x8x4 = 256 blocks, fp32 out
  gemm8<128, float, false><<<256, 512, 0, stream>>>(
      Sb, Vtb, out, 2048, 2048, 2048, 1024, 2048L * 2048, 1024L * 2048,
      2048L * 1024, 1.0f, 8, 8);
}

// Round 3
// 197.537 us; speedup vs baseline: 1.7152x; 1.7152x over previous
//
#include <hip/hip_runtime.h>
#include <hip/hip_bf16.h>
#include <stdint.h>
#include <type_traits>

// ---------------------------------------------------------------------------
// Fused attention: out = softmax((x Wq^T)(x Wk^T)^T / sqrt(d)) (x Wv^T)
// B=4, S=2048, D=1024, fp32 in/out, bf16 MFMA internal compute.
//
// R3: faithful 256-tile 8-phase GEMM engine (T2+T3+T4+T5):
//  - BM=256, BK=64, 8 waves (2Mx4N), per-wave 128x64 output split so each
//    phase (mh,nh) reads exactly one A-half and one B-half of the LDS tile.
//  - T2: st-style XOR swizzle (byte ^= (row&7)<<4), applied on the GLOBAL
//    source address (global_load_lds writes linearly) and on ds_read addrs.
//  - T3/T4: 4 phases per K-tile, each stages one half-tile of tile t+1;
//    counted vmcnt waits (never 0 in steady state), derived race-free:
//      end ph0: vmcnt(2LA | LA)   covers B1 needed by ph1
//      end ph1: vmcnt(LA+LB | 0)  covers A1 needed by ph2
//      end ph3: vmcnt(LA+LB)      covers A0',B0' needed by next ph0
//  - T5: setprio(1) around each 16-MFMA cluster.
// ---------------------------------------------------------------------------

typedef __attribute__((ext_vector_type(8))) short short8;
typedef __attribute__((ext_vector_type(4))) float f32x4;

#define GL_G(p) ((const __attribute__((address_space(1))) void*)(p))
#define GL_L(p) ((__attribute__((address_space(3))) void*)(p))

__device__ __forceinline__ float bf2f(unsigned short u) {
  union { float f; uint32_t i; } c; c.i = ((uint32_t)u) << 16; return c.f;
}
__device__ __forceinline__ unsigned short f2bf(float f) {
  __hip_bfloat16 h = __float2bfloat16(f);
  return *reinterpret_cast<unsigned short*>(&h);
}

// ---------------- cast fp32 -> bf16 (vectorized) ----------------
__global__ __launch_bounds__(256) void cast_f32_to_bf16(
    const float* __restrict__ in, unsigned short* __restrict__ out, long n) {
  long tid = (long)blockIdx.x * blockDim.x + threadIdx.x;
  long stride = (long)gridDim.x * blockDim.x;
  for (long j = tid * 8; j < n; j += stride * 8) {
    float4 a = *(const float4*)(in + j);
    float4 b = *(const float4*)(in + j + 4);
    uint4 pk;
    pk.x = (uint32_t)f2bf(a.x) | ((uint32_t)f2bf(a.y) << 16);
    pk.y = (uint32_t)f2bf(a.z) | ((uint32_t)f2bf(a.w) << 16);
    pk.z = (uint32_t)f2bf(b.x) | ((uint32_t)f2bf(b.y) << 16);
    pk.w = (uint32_t)f2bf(b.z) | ((uint32_t)f2bf(b.w) << 16);
    *(uint4*)(out + j) = pk;
  }
}

template <int N>
__device__ __forceinline__ void waitv() {
  asm volatile("s_waitcnt vmcnt(%0)" :: "n"(N) : "memory");
}

// ---------------- NT GEMM, 256xBN tile, BK=64, 8-phase schedule -----------
// C[m,n] = scale * sum_k A[m,k] B[n,k].  A:[M x K] bf16 (ldA), B:[N x K] (ldB)
// Requires M%256==0, N%BN==0, K%64==0, K/64 >= 2. Grid 1D = nbm*nbn*nz, %8==0.
// If z == ztrans (OUT_T must be ushort): store transposed per-batch
// (hardcoded: 2048 rows/batch, out [1024][2048] per batch).
template <int BN, typename OUT_T>
__global__ __launch_bounds__(512, 2) void gemm8p(
    const unsigned short* __restrict__ A, const unsigned short* __restrict__ B,
    OUT_T* __restrict__ C, int K, int ldA, int ldB, int ldC,
    long sA, long sB, long sC, float scale, int nbm, int nbn, int ztrans) {
  constexpr int BM = 256, BK = 64;
  constexpr int WVN = BN / 4;    // per-wave N: 64 or 32
  constexpr int NREP = WVN / 16; // 4 or 2
  constexpr int NPH = NREP / 2;  // frags per phase: 2 or 1
  constexpr int LA = 2;          // global_load_lds per A-half
  constexpr int LB = BN / 128;   // per B-half: 2 or 1
  constexpr int AHALF = 128 * BK * 2;      // 16384 B
  constexpr int BHALF = (BN / 2) * BK * 2; // 16384 or 8192 B
  __shared__ __align__(16) char smem[4 * AHALF + 4 * BHALF];

  const int tid = threadIdx.x;
  const int wid = tid >> 6, lane = tid & 63;
  const int wm = wid >> 2, wn = wid & 3;
  const int fr = lane & 15;
  const int kq = lane >> 4;  // 0..3

  // XCD-aware bijective swizzle (gridDim %8==0), n-major decode.
  const int NB = gridDim.x;
  const int p = blockIdx.x;
  const int l = (p & 7) * (NB >> 3) + (p >> 3);
  const int pb = nbm * nbn;
  const int z = l / pb;
  const int mn = l - z * pb;
  const int bm = mn / nbn, bn = mn - bm * nbn;
  const unsigned short* Az = A + (long)z * sA;
  const unsigned short* Bz = B + (long)z * sB;
  const long brow = (long)bm * BM, bcol = (long)bn * BN;

  // staging: each load = 512 thr x 16B = 64 rows x 128B. source col is
  // pre-swizzled so linear LDS write == swizzled layout (m173/m201 pattern).
  const int srow = tid >> 3;  // 0..63
  const int scolb = ((tid & 7) * 16) ^ ((srow & 7) << 4);

  auto stageA = [&](int buf, int half, int kt) {
#pragma unroll
    for (int part = 0; part < LA; ++part) {
      const char* g = (const char*)Az +
          ((brow + half * 128 + part * 64 + srow) * (long)ldA + kt) * 2 + scolb;
      __builtin_amdgcn_global_load_lds(
          GL_G(g),
          GL_L(smem + (buf * 2 + half) * AHALF + part * 8192 + wid * 1024),
          16, 0, 0);
    }
  };
  auto stageB = [&](int buf, int half, int kt) {
#pragma unroll
    for (int part = 0; part < LB; ++part) {
      const char* g = (const char*)Bz +
          ((bcol + half * (BN / 2) + part * 64 + srow) * (long)ldB + kt) * 2 +
          scolb;
      __builtin_amdgcn_global_load_lds(
          GL_G(g),
          GL_L(smem + 4 * AHALF + (buf * 2 + half) * BHALF + part * 8192 +
               wid * 1024),
          16, 0, 0);
    }
  };

  f32x4 acc[8][NREP];
#pragma unroll
  for (int m = 0; m < 8; ++m)
#pragma unroll
    for (int n = 0; n < NREP; ++n) acc[m][n] = (f32x4){0.f, 0.f, 0.f, 0.f};

  // prologue: tile 0 fully staged, drain once (outside main loop is OK)
  stageA(0, 0, 0); stageB(0, 0, 0); stageB(0, 1, 0); stageA(0, 1, 0);
  asm volatile("s_waitcnt vmcnt(0)" ::: "memory");
  __builtin_amdgcn_s_barrier();
  asm volatile("" ::: "memory");

  const int nt = K / BK;
  for (int t = 0; t < nt; ++t) {
    const int cur = t & 1;
    const int nxt = cur ^ 1;
    const int ktn = (t + 1) * BK;
    const bool more = (t + 1) < nt;
#pragma unroll
    for (int ph = 0; ph < 4; ++ph) {
      const int mh = ph >> 1, nh = ph & 1;
      // ds-read this phase's fragments (data guaranteed by prev phase's wait)
      short8 af[4][2];
      short8 bfx[NPH][2];
#pragma unroll
      for (int i = 0; i < 4; ++i)
#pragma unroll
        for (int ks = 0; ks < 2; ++ks) {
          const int r = wm * 64 + i * 16 + fr;
          const int off = (cur * 2 + mh) * AHALF + r * 128 +
                          ((ks * 64 + kq * 16) ^ ((fr & 7) << 4));
          af[i][ks] = *(const short8*)(smem + off);
        }
#pragma unroll
      for (int j = 0; j < NPH; ++j)
#pragma unroll
        for (int ks = 0; ks < 2; ++ks) {
          const int r = wn * (WVN / 2) + j * 16 + fr;
          const int off = 4 * AHALF + (cur * 2 + nh) * BHALF + r * 128 +
                          ((ks * 64 + kq * 16) ^ ((fr & 7) << 4));
          bfx[j][ks] = *(const short8*)(smem + off);
        }
      // stage one half-tile of tile t+1 (order: A0, B0, B1, A1)
      if (more) {
        if (ph == 0) stageA(nxt, 0, ktn);
        else if (ph == 1) stageB(nxt, 0, ktn);
        else if (ph == 2) stageB(nxt, 1, ktn);
        else stageA(nxt, 1, ktn);
      }
      asm volatile("" ::: "memory");
      __builtin_amdgcn_s_barrier();
      asm volatile("s_waitcnt lgkmcnt(0)" ::: "memory");
      __builtin_amdgcn_sched_barrier(0);
      __builtin_amdgcn_s_setprio(1);
#pragma unroll
      for (int i = 0; i < 4; ++i)
#pragma unroll
        for (int j = 0; j < NPH; ++j)
#pragma unroll
          for (int ks = 0; ks < 2; ++ks)
            acc[mh * 4 + i][nh * NPH + j] =
                __builtin_amdgcn_mfma_f32_16x16x32_bf16(
                    af[i][ks], bfx[j][ks], acc[mh * 4 + i][nh * NPH + j], 0, 0,
                    0);
      __builtin_amdgcn_s_setprio(0);
      // counted waits (cover NEXT phase's ds_reads; per-wave count + barrier
      // => collective guarantee). Never 0 in steady state.
      if (ph == 0) {
        if (more) waitv<2 * LA>(); else waitv<LA>();
      } else if (ph == 1) {
        if (more) waitv<LA + LB>(); else waitv<0>();
      } else if (ph == 3) {
        if (more) waitv<LA + LB>();
      }
      asm volatile("" ::: "memory");
      __builtin_amdgcn_s_barrier();
      asm volatile("" ::: "memory");
    }
  }

  // epilogue: C/D layout col = lane&15, row = (lane>>4)*4 + r
#pragma unroll
  for (int m = 0; m < 8; ++m) {
    const int mh = m >> 2, i = m & 3;
    const long rowg0 = brow + mh * 128 + wm * 64 + i * 16 + kq * 4;
#pragma unroll
    for (int n = 0; n < NREP; ++n) {
      const int nh = n / NPH, j = n % NPH;
      const long colg = bcol + nh * (BN / 2) + wn * (WVN / 2) + j * 16 + fr;
      f32x4 v = acc[m][n];
      bool stored = false;
      if constexpr (std::is_same<OUT_T, unsigned short>::value) {
        if (z == ztrans) {
          // transposed per-batch store: Vt[b][e][s], b from row (2048 rows/b)
          unsigned short* Ct = (unsigned short*)(C + z * sC);
          const long bb = rowg0 >> 11;
          ushort4 pk;
          pk.x = f2bf(v[0] * scale);
          pk.y = f2bf(v[1] * scale);
          pk.z = f2bf(v[2] * scale);
          pk.w = f2bf(v[3] * scale);
          *(ushort4*)(Ct + bb * (2048L * 1024) + colg * 2048 + (rowg0 & 2047)) =
              pk;
          stored = true;
        }
      }
      if (!stored) {
        OUT_T* Cz = C + (long)z * sC;
#pragma unroll
        for (int r = 0; r < 4; ++r) {
          float val = v[r] * scale;
          if constexpr (std::is_same<OUT_T, float>::value)
            Cz[(rowg0 + r) * ldC + colg] = val;
          else
            Cz[(rowg0 + r) * ldC + colg] = f2bf(val);
        }
      }
    }
  }
}

// ---------------- row softmax in-place on bf16 [rows x 2048] ----------------
__global__ __launch_bounds__(256) void softmax_inplace(
    unsigned short* __restrict__ S) {
  unsigned short* row = S + (size_t)blockIdx.x * 2048;
  const int tid = threadIdx.x;
  const int wid = tid >> 6;
  const int lane = tid & 63;

  uint4 raw = *(const uint4*)(row + tid * 8);
  float v[8];
  v[0] = bf2f(raw.x & 0xffff); v[1] = bf2f(raw.x >> 16);
  v[2] = bf2f(raw.y & 0xffff); v[3] = bf2f(raw.y >> 16);
  v[4] = bf2f(raw.z & 0xffff); v[5] = bf2f(raw.z >> 16);
  v[6] = bf2f(raw.w & 0xffff); v[7] = bf2f(raw.w >> 16);

  float mx = v[0];
#pragma unroll
  for (int i = 1; i < 8; ++i) mx = fmaxf(mx, v[i]);
#pragma unroll
  for (int off = 32; off; off >>= 1) mx = fmaxf(mx, __shfl_xor(mx, off));

  __shared__ float sred[8];
  if (lane == 0) sred[wid] = mx;
  __syncthreads();
  mx = fmaxf(fmaxf(sred[0], sred[1]), fmaxf(sred[2], sred[3]));

  float e[8];
  float s = 0.f;
#pragma unroll
  for (int i = 0; i < 8; ++i) {
    e[i] = __expf(v[i] - mx);
    s += e[i];
  }
#pragma unroll
  for (int off = 32; off; off >>= 1) s += __shfl_xor(s, off);
  if (lane == 0) sred[4 + wid] = s;
  __syncthreads();
  s = (sred[4] + sred[5]) + (sred[6] + sred[7]);
  float inv = 1.0f / s;

  uint4 pk;
  pk.x = (uint32_t)f2bf(e[0] * inv) | ((uint32_t)f2bf(e[1] * inv) << 16);
  pk.y = (uint32_t)f2bf(e[2] * inv) | ((uint32_t)f2bf(e[3] * inv) << 16);
  pk.z = (uint32_t)f2bf(e[4] * inv) | ((uint32_t)f2bf(e[5] * inv) << 16);
  pk.w = (uint32_t)f2bf(e[6] * inv) | ((uint32_t)f2bf(e[7] * inv) << 16);
  *(uint4*)(row + tid * 8) = pk;
}

// ---------------------------------------------------------------------------
extern "C" void kernel_launch(void* const* d_in, const int* in_sizes, int n_in,
                              void* d_out, int out_size, void* d_ws,
                              size_t ws_size, hipStream_t stream) {
  const float* x = (const float*)d_in[0];
  const float* Wq = (const float*)d_in[1];
  const float* Wk = (const float*)d_in[2];
  const float* Wv = (const float*)d_in[3];
  float* out = (float*)d_out;

  const long XE = 4L * 2048 * 1024;  // 8,388,608 elems
  const long WE = 1024L * 1024;      // 1,048,576 elems
  const long SE = 4L * 2048 * 2048;  // 16,777,216 elems

  unsigned short* xb = (unsigned short*)d_ws;
  unsigned short* Wqb = xb + XE;     // Wq,Wk,Wv contiguous (strideB = WE)
  unsigned short* Qb = Wqb + 3 * WE; // Qb,Kb,Vtb contiguous (strideC = XE)
  unsigned short* Kb = Qb + XE;
  unsigned short* Vtb = Kb + XE;     // [b][e][s] (transposed V)
  unsigned short* Sb = Vtb + XE;     // [b][q][k] scores -> probs
  if (ws_size < (size_t)(4 * XE + 3 * WE + SE) * 2) return;  // loud failure

  cast_f32_to_bf16<<<1024, 256, 0, stream>>>(x, xb, XE);
  cast_f32_to_bf16<<<768, 256, 0, stream>>>(Wq, Wqb, WE);
  cast_f32_to_bf16<<<768, 256, 0, stream>>>(Wk, Wqb + WE, WE);
  cast_f32_to_bf16<<<768, 256, 0, stream>>>(Wv, Wqb + 2 * WE, WE);

  // fused QKV projection: z in {0,1,2} -> Wq/Wk/Wv, C = Qb/Kb/Vtb(z=2 trans).
  // M=8192 (nbm=32), N=1024 (BN=256 -> nbn=4): 32*4*3 = 384 blocks.
  gemm8p<256, unsigned short><<<384, 512, 0, stream>>>(
      xb, Wqb, Qb, 1024, 1024, 1024, 1024, 0, WE, XE, 1.0f, 32, 4,
      /*ztrans=*/2);
  // S[b][q][k] = Qb Kb^T / 32, per batch: 8x8x4 = 256 blocks (256x256 tile)
  gemm8p<256, unsigned short><<<256, 512, 0, stream>>>(
      Qb, Kb, Sb, 1024, 1024, 1024, 2048, 2048L * 1024, 2048L * 1024,
      2048L * 2048, 0.03125f, 8, 8, -1);
  // softmax rows (4*2048 rows of 2048)
  softmax_inplace<<<8192, 256, 0, stream>>>(Sb);
  // out[b][q][e] = P Vt^T, per batch: BN=128 -> 8x8x4 = 256 blocks, fp32 out
  gemm8p<128, float><<<256, 512, 0, stream>>>(
      Sb, Vtb, out, 2048, 2048, 2048, 1024, 2048L * 2048, 1024L * 2048,
      2048L * 1024, 1.0f, 8, 8, -1);
}

// Round 4
// 179.383 us; speedup vs baseline: 1.8888x; 1.1012x over previous
//
#include <hip/hip_runtime.h>
#include <hip/hip_bf16.h>
#include <stdint.h>
#include <type_traits>

// ---------------------------------------------------------------------------
// Fused attention: out = softmax((x Wq^T)(x Wk^T)^T / sqrt(d)) (x Wv^T)
// B=4, S=2048, D=1024, fp32 in/out, bf16 MFMA internal compute.
//
// R4: Gray-code phase order (0,0)->(0,1)->(1,1)->(1,0) with register reuse:
// A-half regs reloaded only at ph0/ph2, B0/B1 in separate reg sets.
// ds_read_b128 per K-tile: 24 (was 48). Counted vmcnt re-derived:
//   stage order A0,B0,B1,A1; end-ph0 vmcnt(2LA), end-ph1 vmcnt(LA+LB),
//   end-ph2 none, end-ph3 vmcnt(LA+LB); tail: LA / 0 / none / none.
// ---------------------------------------------------------------------------

typedef __attribute__((ext_vector_type(8))) short short8;
typedef __attribute__((ext_vector_type(4))) float f32x4;

#define GL_G(p) ((const __attribute__((address_space(1))) void*)(p))
#define GL_L(p) ((__attribute__((address_space(3))) void*)(p))

__device__ __forceinline__ float bf2f(unsigned short u) {
  union { float f; uint32_t i; } c; c.i = ((uint32_t)u) << 16; return c.f;
}
__device__ __forceinline__ unsigned short f2bf(float f) {
  __hip_bfloat16 h = __float2bfloat16(f);
  return *reinterpret_cast<unsigned short*>(&h);
}

// ---------------- cast fp32 -> bf16 (vectorized) ----------------
__global__ __launch_bounds__(256) void cast_f32_to_bf16(
    const float* __restrict__ in, unsigned short* __restrict__ out, long n) {
  long tid = (long)blockIdx.x * blockDim.x + threadIdx.x;
  long stride = (long)gridDim.x * blockDim.x;
  for (long j = tid * 8; j < n; j += stride * 8) {
    float4 a = *(const float4*)(in + j);
    float4 b = *(const float4*)(in + j + 4);
    uint4 pk;
    pk.x = (uint32_t)f2bf(a.x) | ((uint32_t)f2bf(a.y) << 16);
    pk.y = (uint32_t)f2bf(a.z) | ((uint32_t)f2bf(a.w) << 16);
    pk.z = (uint32_t)f2bf(b.x) | ((uint32_t)f2bf(b.y) << 16);
    pk.w = (uint32_t)f2bf(b.z) | ((uint32_t)f2bf(b.w) << 16);
    *(uint4*)(out + j) = pk;
  }
}

template <int N>
__device__ __forceinline__ void waitv() {
  asm volatile("s_waitcnt vmcnt(%0)" :: "n"(N) : "memory");
}
__device__ __forceinline__ void barrier_() {
  asm volatile("" ::: "memory");
  __builtin_amdgcn_s_barrier();
  asm volatile("" ::: "memory");
}

// ---------------- NT GEMM, 256xBN tile, BK=64, 8-phase schedule -----------
// C[m,n] = scale * sum_k A[m,k] B[n,k].  A:[M x K] bf16 (ldA), B:[N x K] (ldB)
// Requires M%256==0, N%BN==0, K%64==0, K/64 >= 2. Grid 1D = nbm*nbn*nz, %8==0.
// If z == ztrans (OUT_T must be ushort): store transposed per-batch
// (hardcoded: 2048 rows/batch, out [1024][2048] per batch).
template <int BN, typename OUT_T>
__global__ __launch_bounds__(512, 2) void gemm8p(
    const unsigned short* __restrict__ A, const unsigned short* __restrict__ B,
    OUT_T* __restrict__ C, int K, int ldA, int ldB, int ldC,
    long sA, long sB, long sC, float scale, int nbm, int nbn, int ztrans) {
  constexpr int BM = 256, BK = 64;
  constexpr int WVN = BN / 4;    // per-wave N: 64 or 32
  constexpr int NREP = WVN / 16; // 4 or 2
  constexpr int NPH = NREP / 2;  // frags per phase: 2 or 1
  constexpr int LA = 2;          // global_load_lds per A-half
  constexpr int LB = BN / 128;   // per B-half: 2 or 1
  constexpr int AHALF = 128 * BK * 2;      // 16384 B
  constexpr int BHALF = (BN / 2) * BK * 2; // 16384 or 8192 B
  __shared__ __align__(16) char smem[4 * AHALF + 4 * BHALF];

  const int tid = threadIdx.x;
  const int wid = tid >> 6, lane = tid & 63;
  const int wm = wid >> 2, wn = wid & 3;
  const int fr = lane & 15;
  const int kq = lane >> 4;  // 0..3

  // XCD-aware bijective swizzle (gridDim %8==0), n-major decode.
  const int NB = gridDim.x;
  const int p = blockIdx.x;
  const int l = (p & 7) * (NB >> 3) + (p >> 3);
  const int pb = nbm * nbn;
  const int z = l / pb;
  const int mn = l - z * pb;
  const int bm = mn / nbn, bn = mn - bm * nbn;
  const unsigned short* Az = A + (long)z * sA;
  const unsigned short* Bz = B + (long)z * sB;
  const long brow = (long)bm * BM, bcol = (long)bn * BN;

  // staging: each load = 512 thr x 16B = 64 rows x 128B. source col is
  // pre-swizzled so linear LDS write == swizzled layout (m173/m201 pattern).
  const int srow = tid >> 3;  // 0..63
  const int scolb = ((tid & 7) * 16) ^ ((srow & 7) << 4);

  auto stageA = [&](int buf, int half, int kt) {
#pragma unroll
    for (int part = 0; part < LA; ++part) {
      const char* g = (const char*)Az +
          ((brow + half * 128 + part * 64 + srow) * (long)ldA + kt) * 2 + scolb;
      __builtin_amdgcn_global_load_lds(
          GL_G(g),
          GL_L(smem + (buf * 2 + half) * AHALF + part * 8192 + wid * 1024),
          16, 0, 0);
    }
  };
  auto stageB = [&](int buf, int half, int kt) {
#pragma unroll
    for (int part = 0; part < LB; ++part) {
      const char* g = (const char*)Bz +
          ((bcol + half * (BN / 2) + part * 64 + srow) * (long)ldB + kt) * 2 +
          scolb;
      __builtin_amdgcn_global_load_lds(
          GL_G(g),
          GL_L(smem + 4 * AHALF + (buf * 2 + half) * BHALF + part * 8192 +
               wid * 1024),
          16, 0, 0);
    }
  };

  f32x4 acc[8][NREP];
#pragma unroll
  for (int m = 0; m < 8; ++m)
#pragma unroll
    for (int n = 0; n < NREP; ++n) acc[m][n] = (f32x4){0.f, 0.f, 0.f, 0.f};

  short8 af[4][2];         // current A-half (reloaded ph0 / ph2)
  short8 b0[NPH][2];       // B-half 0 (read ph0, reused ph3)
  short8 b1[NPH][2];       // B-half 1 (read ph1, reused ph2)

  auto readA = [&](int cur, int mh) {
#pragma unroll
    for (int i = 0; i < 4; ++i)
#pragma unroll
      for (int ks = 0; ks < 2; ++ks) {
        const int r = wm * 64 + i * 16 + fr;
        const int off = (cur * 2 + mh) * AHALF + r * 128 +
                        ((ks * 64 + kq * 16) ^ ((fr & 7) << 4));
        af[i][ks] = *(const short8*)(smem + off);
      }
  };
  auto readB = [&](short8 (&bf_)[NPH][2], int cur, int nh) {
#pragma unroll
    for (int j = 0; j < NPH; ++j)
#pragma unroll
      for (int ks = 0; ks < 2; ++ks) {
        const int r = wn * (WVN / 2) + j * 16 + fr;
        const int off = 4 * AHALF + (cur * 2 + nh) * BHALF + r * 128 +
                        ((ks * 64 + kq * 16) ^ ((fr & 7) << 4));
        bf_[j][ks] = *(const short8*)(smem + off);
      }
  };
  auto mfmaCl = [&](int mh, int nh, short8 (&bf_)[NPH][2]) {
    __builtin_amdgcn_s_setprio(1);
#pragma unroll
    for (int i = 0; i < 4; ++i)
#pragma unroll
      for (int j = 0; j < NPH; ++j)
#pragma unroll
        for (int ks = 0; ks < 2; ++ks)
          acc[mh * 4 + i][nh * NPH + j] =
              __builtin_amdgcn_mfma_f32_16x16x32_bf16(
                  af[i][ks], bf_[j][ks], acc[mh * 4 + i][nh * NPH + j], 0, 0,
                  0);
    __builtin_amdgcn_s_setprio(0);
  };
  auto lgkm0sb = [&]() {
    asm volatile("s_waitcnt lgkmcnt(0)" ::: "memory");
    __builtin_amdgcn_sched_barrier(0);
  };

  // prologue: tile 0 fully staged, drain once (outside main loop is OK)
  stageA(0, 0, 0); stageB(0, 0, 0); stageB(0, 1, 0); stageA(0, 1, 0);
  asm volatile("s_waitcnt vmcnt(0)" ::: "memory");
  barrier_();

  const int nt = K / BK;
  for (int t = 0; t < nt; ++t) {
    const int cur = t & 1;
    const int nxt = cur ^ 1;
    const int ktn = (t + 1) * BK;
    const bool more = (t + 1) < nt;

    // ---- PH0: (mh=0, nh=0) — reads A0, B0; stages A0' ----
    readA(cur, 0);
    readB(b0, cur, 0);
    if (more) stageA(nxt, 0, ktn);
    barrier_();
    lgkm0sb();
    mfmaCl(0, 0, b0);
    if (more) waitv<2 * LA>(); else waitv<LA>();
    barrier_();

    // ---- PH1: (mh=0, nh=1) — reads B1; stages B0' ----
    readB(b1, cur, 1);
    if (more) stageB(nxt, 0, ktn);
    barrier_();
    lgkm0sb();
    mfmaCl(0, 1, b1);
    if (more) waitv<LA + LB>(); else waitv<0>();
    barrier_();

    // ---- PH2: (mh=1, nh=1) — reads A1; stages B1' ----
    readA(cur, 1);
    if (more) stageB(nxt, 1, ktn);
    barrier_();
    lgkm0sb();
    mfmaCl(1, 1, b1);
    barrier_();

    // ---- PH3: (mh=1, nh=0) — no reads; stages A1' ----
    if (more) stageA(nxt, 1, ktn);
    barrier_();
    mfmaCl(1, 0, b0);
    if (more) waitv<LA + LB>();
    barrier_();
  }

  // epilogue: C/D layout col = lane&15, row = (lane>>4)*4 + r
#pragma unroll
  for (int m = 0; m < 8; ++m) {
    const int mh = m >> 2, i = m & 3;
    const long rowg0 = brow + mh * 128 + wm * 64 + i * 16 + kq * 4;
#pragma unroll
    for (int n = 0; n < NREP; ++n) {
      const int nh = n / NPH, j = n % NPH;
      const long colg = bcol + nh * (BN / 2) + wn * (WVN / 2) + j * 16 + fr;
      f32x4 v = acc[m][n];
      bool stored = false;
      if constexpr (std::is_same<OUT_T, unsigned short>::value) {
        if (z == ztrans) {
          // transposed per-batch store: Vt[b][e][s], b from row (2048 rows/b)
          unsigned short* Ct = (unsigned short*)(C + z * sC);
          const long bb = rowg0 >> 11;
          ushort4 pk;
          pk.x = f2bf(v[0] * scale);
          pk.y = f2bf(v[1] * scale);
          pk.z = f2bf(v[2] * scale);
          pk.w = f2bf(v[3] * scale);
          *(ushort4*)(Ct + bb * (2048L * 1024) + colg * 2048 + (rowg0 & 2047)) =
              pk;
          stored = true;
        }
      }
      if (!stored) {
        OUT_T* Cz = C + (long)z * sC;
#pragma unroll
        for (int r = 0; r < 4; ++r) {
          float val = v[r] * scale;
          if constexpr (std::is_same<OUT_T, float>::value)
            Cz[(rowg0 + r) * ldC + colg] = val;
          else
            Cz[(rowg0 + r) * ldC + colg] = f2bf(val);
        }
      }
    }
  }
}

// ---------------- row softmax in-place on bf16 [rows x 2048] ----------------
__global__ __launch_bounds__(256) void softmax_inplace(
    unsigned short* __restrict__ S) {
  unsigned short* row = S + (size_t)blockIdx.x * 2048;
  const int tid = threadIdx.x;
  const int wid = tid >> 6;
  const int lane = tid & 63;

  uint4 raw = *(const uint4*)(row + tid * 8);
  float v[8];
  v[0] = bf2f(raw.x & 0xffff); v[1] = bf2f(raw.x >> 16);
  v[2] = bf2f(raw.y & 0xffff); v[3] = bf2f(raw.y >> 16);
  v[4] = bf2f(raw.z & 0xffff); v[5] = bf2f(raw.z >> 16);
  v[6] = bf2f(raw.w & 0xffff); v[7] = bf2f(raw.w >> 16);

  float mx = v[0];
#pragma unroll
  for (int i = 1; i < 8; ++i) mx = fmaxf(mx, v[i]);
#pragma unroll
  for (int off = 32; off; off >>= 1) mx = fmaxf(mx, __shfl_xor(mx, off));

  __shared__ float sred[8];
  if (lane == 0) sred[wid] = mx;
  __syncthreads();
  mx = fmaxf(fmaxf(sred[0], sred[1]), fmaxf(sred[2], sred[3]));

  float e[8];
  float s = 0.f;
#pragma unroll
  for (int i = 0; i < 8; ++i) {
    e[i] = __expf(v[i] - mx);
    s += e[i];
  }
#pragma unroll
  for (int off = 32; off; off >>= 1) s += __shfl_xor(s, off);
  if (lane == 0) sred[4 + wid] = s;
  __syncthreads();
  s = (sred[4] + sred[5]) + (sred[6] + sred[7]);
  float inv = 1.0f / s;

  uint4 pk;
  pk.x = (uint32_t)f2bf(e[0] * inv) | ((uint32_t)f2bf(e[1] * inv) << 16);
  pk.y = (uint32_t)f2bf(e[2] * inv) | ((uint32_t)f2bf(e[3] * inv) << 16);
  pk.z = (uint32_t)f2bf(e[4] * inv) | ((uint32_t)f2bf(e[5] * inv) << 16);
  pk.w = (uint32_t)f2bf(e[6] * inv) | ((uint32_t)f2bf(e[7] * inv) << 16);
  *(uint4*)(row + tid * 8) = pk;
}

// ---------------------------------------------------------------------------
extern "C" void kernel_launch(void* const* d_in, const int* in_sizes, int n_in,
                              void* d_out, int out_size, void* d_ws,
                              size_t ws_size, hipStream_t stream) {
  const float* x = (const float*)d_in[0];
  const float* Wq = (const float*)d_in[1];
  const float* Wk = (const float*)d_in[2];
  const float* Wv = (const float*)d_in[3];
  float* out = (float*)d_out;

  const long XE = 4L * 2048 * 1024;  // 8,388,608 elems
  const long WE = 1024L * 1024;      // 1,048,576 elems
  const long SE = 4L * 2048 * 2048;  // 16,777,216 elems

  unsigned short* xb = (unsigned short*)d_ws;
  unsigned short* Wqb = xb + XE;     // Wq,Wk,Wv contiguous (strideB = WE)
  unsigned short* Qb = Wqb + 3 * WE; // Qb,Kb,Vtb contiguous (strideC = XE)
  unsigned short* Kb = Qb + XE;
  unsigned short* Vtb = Kb + XE;     // [b][e][s] (transposed V)
  unsigned short* Sb = Vtb + XE;     // [b][q][k] scores -> probs
  if (ws_size < (size_t)(4 * XE + 3 * WE + SE) * 2) return;  // loud failure

  cast_f32_to_bf16<<<1024, 256, 0, stream>>>(x, xb, XE);
  cast_f32_to_bf16<<<768, 256, 0, stream>>>(Wq, Wqb, WE);
  cast_f32_to_bf16<<<768, 256, 0, stream>>>(Wk, Wqb + WE, WE);
  cast_f32_to_bf16<<<768, 256, 0, stream>>>(Wv, Wqb + 2 * WE, WE);

  // fused QKV projection: z in {0,1,2} -> Wq/Wk/Wv, C = Qb/Kb/Vtb(z=2 trans).
  // M=8192 (nbm=32), N=1024 (BN=256 -> nbn=4): 32*4*3 = 384 blocks.
  gemm8p<256, unsigned short><<<384, 512, 0, stream>>>(
      xb, Wqb, Qb, 1024, 1024, 1024, 1024, 0, WE, XE, 1.0f, 32, 4,
      /*ztrans=*/2);
  // S[b][q][k] = Qb Kb^T / 32, per batch: 8x8x4 = 256 blocks (256x256 tile)
  gemm8p<256, unsigned short><<<256, 512, 0, stream>>>(
      Qb, Kb, Sb, 1024, 1024, 1024, 2048, 2048L * 1024, 2048L * 1024,
      2048L * 2048, 0.03125f, 8, 8, -1);
  // softmax rows (4*2048 rows of 2048)
  softmax_inplace<<<8192, 256, 0, stream>>>(Sb);
  // out[b][q][e] = P Vt^T, per batch: BN=128 -> 8x8x4 = 256 blocks, fp32 out
  gemm8p<128, float><<<256, 512, 0, stream>>>(
      Sb, Vtb, out, 2048, 2048, 2048, 1024, 2048L * 2048, 1024L * 2048,
      2048L * 1024, 1.0f, 8, 8, -1);
}